// Round 6
// baseline (103.618 us; speedup 1.0000x reference)
//
#include <hip/hip_runtime.h>

// YOLO layer: x (32, 255, 76, 76) fp32 -> out (32, 76*76*3, 85) fp32
// out flat = b*(76*76*255) + h*(76*255) + w*255 + (a*85 + attr)
//          = f(x[b][a*85+attr][h][w])
//   attr 0: (sigmoid(v) + w) * 8     attr 2: exp(v) * {10,16,33}[a]
//   attr 1: (sigmoid(v) + h) * 8     attr 3: exp(v) * {13,30,23}[a]
//   else  : sigmoid(v)
//
// PERSISTENT PIPELINE, 2 blocks/CU, PING-PONG HALF-TILES (round-6).
// Round 5's loop alternated pure-LDS phases (scatter) and pure-vmem phases
// (store) around barriers: one pipe always idle. Split each tile by w into
// half A (w 0..39, 2550 f4) and half B (w 40..75, 2295 f4), separate LDS
// buffers (same 77.5 KB total -> still 2 blocks/CU). Steady state:
//   phase 1: issue A(t+1) | scatter B(t) | store A(t)   -- barrier
//   phase 2: issue B(t+1) | scatter A(t+1) | store B(t) -- barrier
// Every phase drives LDS-write AND global-store AND prefetch, so barriers no
// longer fence an idle pipe. Hazards: each buffer's store-read and next
// scatter-write are separated by exactly one barrier; vmcnt FIFO order means
// waits on the older half's loads never drain the newer prefetch.
// Per-thread state: stA[3]+stB[3] = 24 VGPR, indices recomputed per use
// (round-5 lesson: descriptor arrays under the 64-VGPR cap spill to scratch
// and show up as +35 MB WRITE_SIZE).

typedef float f4 __attribute__((ext_vector_type(4)));

constexpr int NBATCH = 32;
constexpr int NH = 76;
constexpr int NW = 76;
constexpr int C = 255;                 // 3 anchors * 85
constexpr int ROW_F4 = NW / 4;         // 19 f4 per input row
constexpr int BLK_F4 = C * ROW_F4;     // 4845 f4 per tile
constexpr int TILES = NBATCH * NH;     // 2432
constexpr int NTH = 1024;
constexpr int GRID = 512;              // 2 blocks per CU
constexpr int NXCD = 8;
constexpr int PER_XCD = TILES / NXCD;        // 304
constexpr int BPX = GRID / NXCD;             // 64 blocks per XCD
constexpr float STRIDE = 8.0f;

// half A: c in [0,10)  -> 255*10 = 2550 f4 (w 0..39)
// half B: c in [10,19) -> 255*9  = 2295 f4 (w 40..75)
constexpr int AF4 = 2550;
constexpr int BF4 = 2295;
constexpr int TAILA = AF4 - 2 * NTH;   // 502 active threads at k==2
constexpr int TAILB = BF4 - 2 * NTH;   // 247 active threads at k==2

__global__ __launch_bounds__(NTH, 8) void yolo_kernel(const f4* __restrict__ x4,
                                                      f4* __restrict__ out4) {
    __shared__ f4 bufA[AF4];           // 40800 B
    __shared__ f4 bufB[BF4];           // 36720 B  (total 77520 -> 2 blocks/CU)
    float* __restrict__ tA = (float*)bufA;
    float* __restrict__ tB = (float*)bufB;

    const int tid = threadIdx.x;

    // ---- XCD-contiguous tile assignment ----
    const int x = blockIdx.x & (NXCD - 1);
    const int j = blockIdx.x >> 3;
    const int base_t = x * PER_XCD;
    const int ntile = 4 + (j < (PER_XCD - 4 * BPX) ? 1 : 0);   // 4 or 5

    f4 stA[3], stB[3];

    auto issueA = [&](int t) {
        const int b = t / NH;
        const int h = t - b * NH;
        const size_t inb = (size_t)b * (C * NH * ROW_F4) + (size_t)h * ROW_F4;
#pragma unroll
        for (int k = 0; k < 3; ++k) {
            if (k == 2 && tid >= TAILA) continue;
            const int i = tid + k * NTH;
            const int row = i / 10;            // channel
            const int cl = i - row * 10;       // c 0..9
            stA[k] = x4[inb + (size_t)row * (NH * ROW_F4) + cl];
        }
    };
    auto issueB = [&](int t) {
        const int b = t / NH;
        const int h = t - b * NH;
        const size_t inb = (size_t)b * (C * NH * ROW_F4) + (size_t)h * ROW_F4;
#pragma unroll
        for (int k = 0; k < 3; ++k) {
            if (k == 2 && tid >= TAILB) continue;
            const int i = tid + k * NTH;
            const int row = i / 9;             // channel
            const int cl = i - row * 9;        // c-10, 0..8
            stB[k] = x4[inb + (size_t)row * (NH * ROW_F4) + cl + 10];
        }
    };

    // fused transform + scatter-transpose (descriptors recomputed, no arrays)
    auto xsA = [&](int t) {
        const float hf = (float)(t % NH);
#pragma unroll
        for (int k = 0; k < 3; ++k) {
            if (k == 2 && tid >= TAILA) continue;
            const int i = tid + k * NTH;
            const int row = i / 10;
            const int cl = i - row * 10;
            const int a = (row >= 85 ? 1 : 0) + (row >= 170 ? 1 : 0);
            const int attr = row - 85 * a;
            const bool m3 = (attr == 2) || (attr == 3);
            const bool m12 = attr < 2;
            const float aw = (a == 0) ? 10.f : ((a == 1) ? 16.f : 33.f);
            const float ah = (a == 0) ? 13.f : ((a == 1) ? 30.f : 23.f);
            const float aux3 = (attr == 2) ? aw : ah;
            const float w0 = (float)(4 * cl);  // actual w base (A: w=4*cl+e)
            const int base = 4 * cl * C + row;
            const f4 v = stA[k];
            f4 r;
#pragma unroll
            for (int e = 0; e < 4; ++e) {
                const float ve = v[e];
                const float E = __expf(m3 ? ve : -ve);
                const float sg = 1.0f / (1.0f + E);
                const float add = (attr == 0) ? (w0 + (float)e) : hf;
                float o = m3 ? (E * aux3) : sg;
                if (m12) o = (sg + add) * STRIDE;
                r[e] = o;
            }
            tA[base]         = r.x;
            tA[base + C]     = r.y;
            tA[base + 2 * C] = r.z;
            tA[base + 3 * C] = r.w;
        }
    };
    auto xsB = [&](int t) {
        const float hf = (float)(t % NH);
#pragma unroll
        for (int k = 0; k < 3; ++k) {
            if (k == 2 && tid >= TAILB) continue;
            const int i = tid + k * NTH;
            const int row = i / 9;
            const int cl = i - row * 9;
            const int a = (row >= 85 ? 1 : 0) + (row >= 170 ? 1 : 0);
            const int attr = row - 85 * a;
            const bool m3 = (attr == 2) || (attr == 3);
            const bool m12 = attr < 2;
            const float aw = (a == 0) ? 10.f : ((a == 1) ? 16.f : 33.f);
            const float ah = (a == 0) ? 13.f : ((a == 1) ? 30.f : 23.f);
            const float aux3 = (attr == 2) ? aw : ah;
            const float w0 = (float)(4 * (cl + 10));  // actual w base
            const int base = 4 * cl * C + row;        // local within bufB
            const f4 v = stB[k];
            f4 r;
#pragma unroll
            for (int e = 0; e < 4; ++e) {
                const float ve = v[e];
                const float E = __expf(m3 ? ve : -ve);
                const float sg = 1.0f / (1.0f + E);
                const float add = (attr == 0) ? (w0 + (float)e) : hf;
                float o = m3 ? (E * aux3) : sg;
                if (m12) o = (sg + add) * STRIDE;
                r[e] = o;
            }
            tB[base]         = r.x;
            tB[base + C]     = r.y;
            tB[base + 2 * C] = r.z;
            tB[base + 3 * C] = r.w;
        }
    };

    auto storeA = [&](int t) {
        const size_t ob = (size_t)t * BLK_F4;
#pragma unroll
        for (int k = 0; k < 3; ++k) {
            const int i = tid + k * NTH;
            if (k < 2 || i < AF4)
                __builtin_nontemporal_store(bufA[i], &out4[ob + i]);
        }
    };
    auto storeB = [&](int t) {
        const size_t ob = (size_t)t * BLK_F4 + AF4;
#pragma unroll
        for (int k = 0; k < 3; ++k) {
            const int i = tid + k * NTH;
            if (k < 2 || i < BF4)
                __builtin_nontemporal_store(bufB[i], &out4[ob + i]);
        }
    };

    // ---- prologue ----
    int ti = 0;
    int t = base_t + j;
    issueA(t);
    issueB(t);
    xsA(t);
    __syncthreads();

    // ---- steady state: two phases per tile, both pipes busy in each ----
    while (true) {
        const bool more = (ti + 1 < ntile);
        const int tn = more ? (base_t + (ti + 1) * BPX + j) : 0;

        // phase 1: prefetch A(t+1) | scatter B(t) | store A(t)
        if (more) issueA(tn);
        xsB(t);
        storeA(t);
        __syncthreads();

        // phase 2: prefetch B(t+1) | scatter A(t+1) | store B(t)
        if (more) {
            issueB(tn);
            xsA(tn);
        }
        storeB(t);
        if (!more) break;
        __syncthreads();

        t = tn;
        ++ti;
    }
}

extern "C" void kernel_launch(void* const* d_in, const int* in_sizes, int n_in,
                              void* d_out, int out_size, void* d_ws, size_t ws_size,
                              hipStream_t stream) {
    const f4* x4 = (const f4*)d_in[0];
    f4* out4 = (f4*)d_out;
    yolo_kernel<<<GRID, NTH, 0, stream>>>(x4, out4);
}

// Round 7
// 91.204 us; speedup vs baseline: 1.1361x; 1.1361x over previous
//
#include <hip/hip_runtime.h>

// YOLO layer: x (32, 255, 76, 76) fp32 -> out (32, 76*76*3, 85) fp32
// out flat = b*(76*76*255) + h*(76*255) + w*255 + (a*85 + attr)
//          = f(x[b][a*85+attr][h][w])
//   attr 0: (sigmoid(v) + w) * 8     attr 2: exp(v) * {10,16,33}[a]
//   attr 1: (sigmoid(v) + h) * 8     attr 3: exp(v) * {13,30,23}[a]
//   else  : sigmoid(v)
//
// PERSISTENT PIPELINE, 2 blocks/CU, SINGLE-STAGE PING-PONG (round-7).
// Round-6 regression root cause: TWO live stage sets (24 VGPR) under the
// 64-VGPR cap spilled to scratch (FETCH 210 MB > input size, WRITE +64 MB).
// The halves are consumed strictly alternately, so ONE shared st[3] (12 VGPR)
// suffices; the WAR (transform reads st, reissue writes st) is enforced by
// program order. Per step (half-tile H_n):
//   transform+scatter H_n | reissue st <- H_{n+1} | store H_{n-1} | barrier
// Same 2 barriers/tile as round 5, but every inter-barrier region drives
// LDS-write AND global-store AND prefetch -> no idle-pipe phases.
// Hazards: each buffer's store-read and next scatter-write are separated by
// exactly one barrier (A: written step 2m, stored step 2m+1, rewritten 2m+2).

typedef float f4 __attribute__((ext_vector_type(4)));

constexpr int NBATCH = 32;
constexpr int NH = 76;
constexpr int NW = 76;
constexpr int C = 255;                 // 3 anchors * 85
constexpr int ROW_F4 = NW / 4;         // 19 f4 per input row
constexpr int BLK_F4 = C * ROW_F4;     // 4845 f4 per tile
constexpr int TILES = NBATCH * NH;     // 2432
constexpr int NTH = 1024;
constexpr int GRID = 512;              // 2 blocks per CU
constexpr int NXCD = 8;
constexpr int PER_XCD = TILES / NXCD;        // 304
constexpr int BPX = GRID / NXCD;             // 64 blocks per XCD
constexpr float STRIDE = 8.0f;

// half A: c in [0,10)  -> 255*10 = 2550 f4 (w 0..39)
// half B: c in [10,19) -> 255*9  = 2295 f4 (w 40..75)
constexpr int AF4 = 2550;
constexpr int BF4 = 2295;
constexpr int TAILA = AF4 - 2 * NTH;   // 502 active threads at k==2
constexpr int TAILB = BF4 - 2 * NTH;   // 247 active threads at k==2

__global__ __launch_bounds__(NTH, 8) void yolo_kernel(const f4* __restrict__ x4,
                                                      f4* __restrict__ out4) {
    __shared__ f4 bufA[AF4];           // 40800 B
    __shared__ f4 bufB[BF4];           // 36720 B (total 77520 -> 2 blocks/CU)
    float* __restrict__ tA = (float*)bufA;
    float* __restrict__ tB = (float*)bufB;

    const int tid = threadIdx.x;

    // ---- XCD-contiguous tile assignment ----
    const int x = blockIdx.x & (NXCD - 1);
    const int j = blockIdx.x >> 3;
    const int base_t = x * PER_XCD;
    const int ntile = 4 + (j < (PER_XCD - 4 * BPX) ? 1 : 0);   // 4 or 5

    f4 st[3];                          // ONE stage set, time-shared A/B

    auto issueA = [&](int t) {
        const int b = t / NH;
        const int h = t - b * NH;
        const size_t inb = (size_t)b * (C * NH * ROW_F4) + (size_t)h * ROW_F4;
#pragma unroll
        for (int k = 0; k < 3; ++k) {
            if (k == 2 && tid >= TAILA) continue;
            const int i = tid + k * NTH;
            const int row = i / 10;            // channel
            const int cl = i - row * 10;       // c 0..9
            st[k] = x4[inb + (size_t)row * (NH * ROW_F4) + cl];
        }
    };
    auto issueB = [&](int t) {
        const int b = t / NH;
        const int h = t - b * NH;
        const size_t inb = (size_t)b * (C * NH * ROW_F4) + (size_t)h * ROW_F4;
#pragma unroll
        for (int k = 0; k < 3; ++k) {
            if (k == 2 && tid >= TAILB) continue;
            const int i = tid + k * NTH;
            const int row = i / 9;             // channel
            const int cl = i - row * 9;        // c-10, 0..8
            st[k] = x4[inb + (size_t)row * (NH * ROW_F4) + cl + 10];
        }
    };

    // fused transform + scatter-transpose (descriptors recomputed, no arrays)
    auto xsA = [&](int t) {
        const float hf = (float)(t % NH);
#pragma unroll
        for (int k = 0; k < 3; ++k) {
            if (k == 2 && tid >= TAILA) continue;
            const int i = tid + k * NTH;
            const int row = i / 10;
            const int cl = i - row * 10;
            const int a = (row >= 85 ? 1 : 0) + (row >= 170 ? 1 : 0);
            const int attr = row - 85 * a;
            const bool m3 = (attr == 2) || (attr == 3);
            const bool m12 = attr < 2;
            const float aw = (a == 0) ? 10.f : ((a == 1) ? 16.f : 33.f);
            const float ah = (a == 0) ? 13.f : ((a == 1) ? 30.f : 23.f);
            const float aux3 = (attr == 2) ? aw : ah;
            const float w0 = (float)(4 * cl);  // actual w (A: w = 4*cl+e)
            const int base = 4 * cl * C + row;
            const f4 v = st[k];
            f4 r;
#pragma unroll
            for (int e = 0; e < 4; ++e) {
                const float ve = v[e];
                const float E = __expf(m3 ? ve : -ve);
                const float sg = 1.0f / (1.0f + E);
                const float add = (attr == 0) ? (w0 + (float)e) : hf;
                float o = m3 ? (E * aux3) : sg;
                if (m12) o = (sg + add) * STRIDE;
                r[e] = o;
            }
            tA[base]         = r.x;
            tA[base + C]     = r.y;
            tA[base + 2 * C] = r.z;
            tA[base + 3 * C] = r.w;
        }
    };
    auto xsB = [&](int t) {
        const float hf = (float)(t % NH);
#pragma unroll
        for (int k = 0; k < 3; ++k) {
            if (k == 2 && tid >= TAILB) continue;
            const int i = tid + k * NTH;
            const int row = i / 9;
            const int cl = i - row * 9;
            const int a = (row >= 85 ? 1 : 0) + (row >= 170 ? 1 : 0);
            const int attr = row - 85 * a;
            const bool m3 = (attr == 2) || (attr == 3);
            const bool m12 = attr < 2;
            const float aw = (a == 0) ? 10.f : ((a == 1) ? 16.f : 33.f);
            const float ah = (a == 0) ? 13.f : ((a == 1) ? 30.f : 23.f);
            const float aux3 = (attr == 2) ? aw : ah;
            const float w0 = (float)(4 * (cl + 10));  // actual w
            const int base = 4 * cl * C + row;        // local within bufB
            const f4 v = st[k];
            f4 r;
#pragma unroll
            for (int e = 0; e < 4; ++e) {
                const float ve = v[e];
                const float E = __expf(m3 ? ve : -ve);
                const float sg = 1.0f / (1.0f + E);
                const float add = (attr == 0) ? (w0 + (float)e) : hf;
                float o = m3 ? (E * aux3) : sg;
                if (m12) o = (sg + add) * STRIDE;
                r[e] = o;
            }
            tB[base]         = r.x;
            tB[base + C]     = r.y;
            tB[base + 2 * C] = r.z;
            tB[base + 3 * C] = r.w;
        }
    };

    auto storeA = [&](int t) {
        const size_t ob = (size_t)t * BLK_F4;
#pragma unroll
        for (int k = 0; k < 3; ++k) {
            const int i = tid + k * NTH;
            if (k < 2 || i < AF4)
                __builtin_nontemporal_store(bufA[i], &out4[ob + i]);
        }
    };
    auto storeB = [&](int t) {
        const size_t ob = (size_t)t * BLK_F4 + AF4;
#pragma unroll
        for (int k = 0; k < 3; ++k) {
            const int i = tid + k * NTH;
            if (k < 2 || i < BF4)
                __builtin_nontemporal_store(bufB[i], &out4[ob + i]);
        }
    };

    // ---- prologue: load+scatter A(t0), refill stage with B(t0) ----
    int m = 0;
    int t = base_t + j;
    issueA(t);
    xsA(t);                            // consumes st (A data)
    issueB(t);                         // refill st (WAR, program order)
    __syncthreads();

    // ---- steady state: every inter-barrier region mixes all three pipes ----
    while (true) {
        const bool more = (m + 1 < ntile);
        const int tn = more ? (base_t + (m + 1) * BPX + j) : 0;

        // step B(t): scatter B(t) | prefetch A(t+1) | store A(t)
        xsB(t);                        // consumes st (B data)
        if (more) issueA(tn);          // refill st
        storeA(t);
        __syncthreads();

        if (!more) {                   // epilogue: bufB already scattered
            storeB(t);
            break;
        }

        // step A(t+1): scatter A(t+1) | prefetch B(t+1) | store B(t)
        xsA(tn);                       // consumes st (A data)
        issueB(tn);                    // refill st
        storeB(t);
        __syncthreads();

        t = tn;
        ++m;
    }
}

extern "C" void kernel_launch(void* const* d_in, const int* in_sizes, int n_in,
                              void* d_out, int out_size, void* d_ws, size_t ws_size,
                              hipStream_t stream) {
    const f4* x4 = (const f4*)d_in[0];
    f4* out4 = (f4*)d_out;
    yolo_kernel<<<GRID, NTH, 0, stream>>>(x4, out4);
}

// Round 8
// 69.654 us; speedup vs baseline: 1.4876x; 1.3094x over previous
//
#include <hip/hip_runtime.h>

// YOLO layer: x (32, 255, 76, 76) fp32 -> out (32, 76*76*3, 85) fp32
// out flat = b*(76*76*255) + h*(76*255) + w*255 + (a*85 + attr)
//          = f(x[b][a*85+attr][h][w])
//   attr 0: (sigmoid(v) + w) * 8     attr 2: exp(v) * {10,16,33}[a]
//   attr 1: (sigmoid(v) + h) * 8     attr 3: exp(v) * {13,30,23}[a]
//   else  : sigmoid(v)
//
// ROUND-8 = ROUND-5 BASE (best: 63.8 us, traffic at ideal 95/188 MB) +
// CU-PAIR ANTIPHASE STAGGER.
// Rounds 6/7 (half-tile ping-pong) both regressed on HBM traffic -> reverted.
// Lockstep model: the 2 co-resident blocks per CU run identical code launched
// simultaneously -> their ~3.2 us store bursts collide; write-bus duty
// 2*3.2/13.4 = 47% EXACTLY matches measured 2.96/6.3 TB/s. Bus idles during
// joint scatter phases, saturates during joint store phases.
// Fix: thread 0 reads HW_ID(SE|SH|CU) + XCC_ID via s_getreg, takes a ticket
// from a per-physical-CU slot in d_ws (memset per launch, capture-safe);
// the SECOND block on each CU sleeps ~7 us (2x s_sleep(127)) before its
// pipeline -> store bursts interleave with the partner's scatter phases.
// Load/store/transform structure untouched (excludes R6/R7 traffic risk).

typedef float f4 __attribute__((ext_vector_type(4)));

constexpr int NBATCH = 32;
constexpr int NH = 76;
constexpr int NW = 76;
constexpr int C = 255;                 // 3 anchors * 85
constexpr int ROW_F4 = NW / 4;         // 19 f4 per input row
constexpr int BLK_F4 = C * ROW_F4;     // 4845 f4 per tile
constexpr int TILES = NBATCH * NH;     // 2432
constexpr int NTH = 1024;
constexpr int KMAX = 5;                // ceil(4845/1024)
constexpr int TAIL = BLK_F4 - 4 * NTH; // 749 (k==4 active threads)
constexpr int GRID = 512;              // 2 blocks per CU
constexpr int NXCD = 8;
constexpr int PER_XCD = TILES / NXCD;        // 304
constexpr int BPX = GRID / NXCD;             // 64 blocks per XCD
constexpr int NSLOTS = 2048;                 // (xcc<<8)|(HW_ID bits 8..15)
constexpr float STRIDE = 8.0f;

__global__ __launch_bounds__(NTH, 8) void yolo_kernel(const f4* __restrict__ x4,
                                                      f4* __restrict__ out4,
                                                      unsigned* __restrict__ cu_slots) {
    __shared__ f4 buf[BLK_F4];         // 77520 B -> 2 blocks/CU
    __shared__ int phase_sh;
    float* __restrict__ tb = (float*)buf;

    const int tid = threadIdx.x;

    // ---- CU-pair phase assignment: 2nd arriver on each physical CU -> odd ----
    if (tid == 0) {
        int par = 0;
        if (cu_slots) {
            // s_getreg imm = (size-1)<<11 | offset<<6 | regid
            const unsigned hw  = __builtin_amdgcn_s_getreg((31u << 11) | 4);  // HW_ID
            const unsigned xcc = __builtin_amdgcn_s_getreg((31u << 11) | 20); // XCC_ID
            const unsigned key = ((xcc & 7u) << 8) | ((hw >> 8) & 0xFFu);     // SE|SH|CU
            par = (int)(atomicAdd(&cu_slots[key], 1u) & 1u);
        }
        phase_sh = par;
    }
    __syncthreads();
    const int stagger = phase_sh;

    // ---- only persistent per-thread array: tile-invariant input offsets ----
    int offk[KMAX];
#pragma unroll
    for (int k = 0; k < KMAX; ++k) {
        const int i = tid + k * NTH;
        const int ii = (k < 4 || tid < TAIL) ? i : 0;
        const int row = ii / ROW_F4;           // channel 0..254
        const int c = ii - row * ROW_F4;       // f4 index along w
        offk[k] = row * (NH * ROW_F4) + c;
    }

    // ---- XCD-contiguous tile assignment ----
    const int x = blockIdx.x & (NXCD - 1);     // XCD (dispatch round-robin)
    const int j = blockIdx.x >> 3;             // block index within XCD, 0..63
    const int base_t = x * PER_XCD;
    const int ntile = 4 + (j < (PER_XCD - 4 * BPX) ? 1 : 0);  // 4 or 5

    f4 stage[KMAX];

    auto issue = [&](int t) {
        const int b = t / NH;
        const int h = t - b * NH;
        const size_t inb = (size_t)b * (C * NH * ROW_F4) + (size_t)h * ROW_F4;
#pragma unroll
        for (int k = 0; k < KMAX; ++k)
            if (k < 4 || tid < TAIL) stage[k] = x4[inb + offk[k]];
    };

    // ---- antiphase: 2nd block per CU delays ~half a tile-period ----
    if (stagger) {
#pragma unroll
        for (int s = 0; s < 2; ++s) __builtin_amdgcn_s_sleep(127);
    }

    int t = base_t + j;                        // tile for idx 0
    issue(t);
    int idx = 0;

    while (true) {
        const float hf = (float)(t % NH);      // block-uniform

        if (idx > 0) __syncthreads();          // prev store-phase reads done

        // ---- fused transform + scatter (descriptors recomputed, no arrays) ----
#pragma unroll
        for (int k = 0; k < KMAX; ++k) {
            if (!(k < 4 || tid < TAIL)) continue;
            const int i = tid + k * NTH;
            const int row = i / ROW_F4;        // channel 0..254
            const int c = i - row * ROW_F4;
            const int a = (row >= 85 ? 1 : 0) + (row >= 170 ? 1 : 0);
            const int attr = row - 85 * a;
            const bool m3 = (attr == 2) || (attr == 3);
            const bool m12 = attr < 2;
            const float aw = (a == 0) ? 10.f : ((a == 1) ? 16.f : 33.f);
            const float ah = (a == 0) ? 13.f : ((a == 1) ? 30.f : 23.f);
            const float aux3 = (attr == 2) ? aw : ah;
            const float w0 = (float)(4 * c);
            const int base = 4 * c * C + row;  // tile[w=4c+e][ch=row]

            const f4 v = stage[k];
            f4 r;
#pragma unroll
            for (int e = 0; e < 4; ++e) {
                const float ve = v[e];
                const float E = __expf(m3 ? ve : -ve);  // one exp per element
                const float sg = 1.0f / (1.0f + E);
                const float add = (attr == 0) ? (w0 + (float)e) : hf;
                float o = m3 ? (E * aux3) : sg;
                if (m12) o = (sg + add) * STRIDE;
                r[e] = o;
            }
            tb[base]         = r.x;
            tb[base + C]     = r.y;
            tb[base + 2 * C] = r.z;
            tb[base + 3 * C] = r.w;
        }

        const size_t ob = (size_t)t * BLK_F4;
        ++idx;
        const bool more = (idx < ntile);
        if (more) {                            // issue next tile's loads now:
            t = base_t + idx * BPX + j;
            issue(t);                          // latency hides under store phase
        }

        __syncthreads();                       // LDS writes visible

        // ---- pure streaming store: contiguous b128 reads + nt stores ----
#pragma unroll
        for (int k = 0; k < KMAX; ++k) {
            const int i = tid + k * NTH;
            if (k < 4 || tid < TAIL)
                __builtin_nontemporal_store(buf[i], &out4[ob + i]);
        }

        if (!more) break;
    }
}

extern "C" void kernel_launch(void* const* d_in, const int* in_sizes, int n_in,
                              void* d_out, int out_size, void* d_ws, size_t ws_size,
                              hipStream_t stream) {
    const f4* x4 = (const f4*)d_in[0];
    f4* out4 = (f4*)d_out;
    unsigned* slots = nullptr;
    if (d_ws && ws_size >= NSLOTS * sizeof(unsigned)) {
        slots = (unsigned*)d_ws;
        hipMemsetAsync(slots, 0, NSLOTS * sizeof(unsigned), stream);
    }
    yolo_kernel<<<GRID, NTH, 0, stream>>>(x4, out4, slots);
}